// Round 9
// baseline (843.425 us; speedup 1.0000x reference)
//
#include <hip/hip_runtime.h>
#include <hip/hip_bf16.h>
#include <stdint.h>

// LinearMultiHeadedAttention: B=16, S=4096, D=1024, H=16, DK=64
// R9: 128x128-tile 4-wave BK=64 GEMM at 3 blocks/CU (the m97 occupancy
//     regime: TLP hides stalls instead of hand scheduling).
//     A = fp32 key/value read directly (conv fused): 8xfloat4/thread issued
//     one step ahead -> cvt -> swizzled ds_write (R8-proven geometry).
//     B = bf16 W via global_load_lds dbuf, pre-swizzled source (R4-proven).
//     LDS 48 KiB (As 16 + Bs 2x16). Exact vmcnt ledger: cvt drains fa only,
//     boundary vmcnt(12) drains exactly B(t+1) staged a full step earlier.

using bf16 = __hip_bfloat16;
typedef __attribute__((ext_vector_type(8))) short short8;  // bf16x8 MFMA frag
typedef __attribute__((ext_vector_type(4))) float f32x4;

#define NB_B 16
#define SEQ 4096
#define DM 1024
#define NH 16
#define DKH 64

__device__ __forceinline__ void gload_lds16(const void* g, void* l) {
  __builtin_amdgcn_global_load_lds((const __attribute__((address_space(1))) void*)g,
                                   (__attribute__((address_space(3))) void*)l, 16, 0, 0);
}

__device__ __forceinline__ short8 cvt8(float4 a, float4 b) {
  union { bf16 h[8]; short8 v; } pk;
  pk.h[0] = __float2bfloat16(a.x); pk.h[1] = __float2bfloat16(a.y);
  pk.h[2] = __float2bfloat16(a.z); pk.h[3] = __float2bfloat16(a.w);
  pk.h[4] = __float2bfloat16(b.x); pk.h[5] = __float2bfloat16(b.y);
  pk.h[6] = __float2bfloat16(b.z); pk.h[7] = __float2bfloat16(b.w);
  return pk.v;
}

// ---------------- fp32 -> bf16 conversion (weights only) ----------------
__global__ __launch_bounds__(256) void conv_kernel(const float* __restrict__ src,
                                                   bf16* __restrict__ dst, long n4) {
  long i = (long)blockIdx.x * blockDim.x + threadIdx.x;
  const long stride = (long)gridDim.x * blockDim.x;
  for (; i < n4; i += stride) {
    float4 v = ((const float4*)src)[i];
    union { ushort4 u; bf16 h[4]; } o;
    o.h[0] = __float2bfloat16(v.x);
    o.h[1] = __float2bfloat16(v.y);
    o.h[2] = __float2bfloat16(v.z);
    o.h[3] = __float2bfloat16(v.w);
    ((ushort4*)dst)[i] = o.u;
  }
}

// ---------------- 128x128 4-wave BK=64 GEMM, fused A-cvt, 3 blk/CU ---------
// C[row][col] = sum_c A[row][c] * W[col][c]  (+bias[col]); KPROJ: elu+1, Ksum.
// A: fp32 [rowsTot][DM]. W: bf16 [DM][DM]. Out TRANSPOSED bf16 outT[col][row].
// LDS rows 128B; frag-read byte = (kk*64 + (lane>>4)*16) ^ ((lane&7)<<4) --
// the R4-measured 0-conflict pattern. A written swizzled; B source pre-swz.
template <int KPROJ>
__global__ __launch_bounds__(256, 3) void gemm128(
    const float* __restrict__ A, const bf16* __restrict__ W,
    const float* __restrict__ bias, bf16* __restrict__ outT,
    float* __restrict__ Ksum, int rowsTot, int b0, int chunk) {
  __shared__ bf16 As[128 * 64];
  __shared__ bf16 Bs[2][128 * 64];
  const int tid = threadIdx.x;
  const int lane = tid & 63;
  const int wid = tid >> 6;   // 0..3
  const int wr = wid >> 1;    // 0..1 -> 64-row half
  const int wc = wid & 1;     // 0..1 -> 64-col half
  // T1 XCD swizzle: contiguous row-panel chunk per XCD, col-tile fastest.
  const int wgid = (blockIdx.x & 7) * chunk + (blockIdx.x >> 3);
  const int row0 = (wgid >> 3) * 128;
  const int col0 = (wgid & 7) * 128;

  f32x4 acc[4][4] = {};

  const int lr = lane & 15;
  const int xr = (lane & 7) << 4;   // read-side XOR key
  const int lk = (lane >> 4) * 16;  // k-slot byte offset

  // A fp32 source: thread covers row tid>>1, 32 fp32 (= half a 256B row).
  const int ra = tid >> 1;
  const float* Ag = A + (long)(row0 + ra) * DM + (tid & 1) * 32;
  const int awbase = ra * 128;            // LDS row byte base
  const int akey = (ra & 7) << 4;         // write-side XOR key
  const int ac0 = (tid & 1) * 4;          // first of 4 dst chunks

  // B staging (R4 pattern): pre-swizzled global source, linear LDS dest.
  const bf16* Wg = W + (long)(col0 + wid * 32 + (lane >> 3)) * DM +
                   ((lane & 7) ^ (lane >> 3)) * 8;
  const int sdstB = wid * 32 * 64;  // elems

  float4 fa[8];

#define A_ISSUE(T_) { \
  _Pragma("unroll") for (int j = 0; j < 4; ++j) { \
    fa[2 * j]     = *(const float4*)(Ag + (T_) * 64 + j * 8); \
    fa[2 * j + 1] = *(const float4*)(Ag + (T_) * 64 + j * 8 + 4); } }

#define A_WRITE() { \
  _Pragma("unroll") for (int j = 0; j < 4; ++j) \
    *(short8*)((char*)As + awbase + (((ac0 + j) * 16) ^ akey)) = \
        cvt8(fa[2 * j], fa[2 * j + 1]); }

#define B_STAGE(buf, T_) { \
  _Pragma("unroll") for (int j = 0; j < 4; ++j) \
    gload_lds16(Wg + (long)j * 8 * DM + (T_) * 64, (void*)&Bs[buf][sdstB + j * 512]); }

  // ---- prologue: fa<-A(0); B(0); cvt A(0) [compiler drains fa, leaves B(0)];
  //      fa<-A(1); B(1); drain B(0) [outstanding fa(1)=8 + B(1)=4 = 12].
  A_ISSUE(0)
  B_STAGE(0, 0)
  A_WRITE()
  A_ISSUE(1)
  B_STAGE(1, 1)
  asm volatile("s_waitcnt vmcnt(12) lgkmcnt(0)\n\ts_barrier" ::: "memory");

#pragma unroll 1
  for (int t = 0; t < 16; ++t) {
    const char* Bc = (const char*)Bs[t & 1];
    // ---- compute tile t: 2 kk x {8 ds_read_b128 + 16 MFMA}
#pragma unroll
    for (int kk = 0; kk < 2; ++kk) {
      short8 af[4], bfv[4];
#pragma unroll
      for (int m = 0; m < 4; ++m)
        af[m] = *(const short8*)((char*)As + (wr * 64 + m * 16 + lr) * 128 +
                                 ((kk * 64 + lk) ^ xr));
#pragma unroll
      for (int n = 0; n < 4; ++n)
        bfv[n] = *(const short8*)(Bc + (wc * 64 + n * 16 + lr) * 128 +
                                  ((kk * 64 + lk) ^ xr));
      __builtin_amdgcn_s_setprio(1);
#pragma unroll
      for (int m = 0; m < 4; ++m)
#pragma unroll
        for (int n = 0; n < 4; ++n)
          acc[m][n] = __builtin_amdgcn_mfma_f32_16x16x32_bf16(af[m], bfv[n], acc[m][n], 0, 0, 0);
      __builtin_amdgcn_s_setprio(0);
    }
    if (t < 15) {
      // close tile-t LDS reads before overwriting As
      asm volatile("s_waitcnt lgkmcnt(0)\n\ts_barrier" ::: "memory");
      A_WRITE()          // cvt A(t+1); compiler waits fa (issued a full step ago)
      if (t < 14) {
        A_ISSUE(t + 2)
        B_STAGE(t & 1, t + 2)
        // outstanding: B(t+1)=4 oldest + fa(t+2)=8 + B(t+2)=4 -> drain B(t+1)
        asm volatile("s_waitcnt vmcnt(12) lgkmcnt(0)\n\ts_barrier" ::: "memory");
      } else {
        asm volatile("s_waitcnt vmcnt(0) lgkmcnt(0)\n\ts_barrier" ::: "memory");
      }
    }
  }
#undef A_ISSUE
#undef A_WRITE
#undef B_STAGE

  // ---- epilogue: bias (+ elu+1 + Ksum), bf16, transposed store
  const int bglob = b0 + (row0 >> 12);
#pragma unroll
  for (int n = 0; n < 4; ++n) {
    const int colg = col0 + wc * 64 + n * 16 + lr;
    const float bv = bias[colg];
    float csum = 0.f;
#pragma unroll
    for (int m = 0; m < 4; ++m) {
      const int r = row0 + wr * 64 + m * 16 + (lane >> 4) * 4;
      union { ushort4 u; bf16 h[4]; } pk;
#pragma unroll
      for (int i = 0; i < 4; ++i) {
        float v = acc[m][n][i] + bv;
        if (KPROJ) { v = v > 0.f ? v + 1.f : __expf(v); csum += v; }
        pk.h[i] = __float2bfloat16(v);
      }
      *(ushort4*)&outT[(long)colg * rowsTot + r] = pk.u;
    }
    if (KPROJ) {
      csum += __shfl_xor(csum, 16);
      csum += __shfl_xor(csum, 32);
      if (lane < 16) atomicAdd(&Ksum[(long)bglob * DM + colg], csum);
    }
  }
}

// ---------------- KV partials: KVp[sp,b,h] = K^T @ V over s-range ----------
__global__ __launch_bounds__(256) void kv_kernel(
    const bf16* __restrict__ KT, const bf16* __restrict__ VT,
    float* __restrict__ KVp, int rowsTot, int b0) {
  const int sp = blockIdx.x & 3;
  const int h = (blockIdx.x >> 2) & 15;
  const int b_loc = blockIdx.x >> 6;
  const int lane = threadIdx.x & 63;
  const int w = threadIdx.x >> 6;
  const long srow = (long)b_loc * SEQ + sp * (SEQ / 4) + ((lane >> 4) * 8);
  const bf16* Ab = KT + (long)(h * DKH + w * 16 + (lane & 15)) * rowsTot + srow;
  const bf16* Bb = VT + (long)(h * DKH + (lane & 15)) * rowsTot + srow;
  f32x4 acc[4] = {};
#pragma unroll 4
  for (int s = 0; s < SEQ / 4; s += 32) {
    short8 a = *(const short8*)(Ab + s);
#pragma unroll
    for (int n = 0; n < 4; ++n) {
      short8 bv = *(const short8*)(Bb + (long)n * 16 * rowsTot + s);
      acc[n] = __builtin_amdgcn_mfma_f32_16x16x32_bf16(a, bv, acc[n], 0, 0, 0);
    }
  }
  float* o = KVp + (((long)sp * NB_B + (b0 + b_loc)) * NH + h) * DKH * DKH;
#pragma unroll
  for (int n = 0; n < 4; ++n)
#pragma unroll
    for (int i = 0; i < 4; ++i)
      o[(w * 16 + (lane >> 4) * 4 + i) * DKH + n * 16 + (lane & 15)] = acc[n][i];
}

// ---------------- small fp32 vec-mat ----------------
template <int ELU>
__global__ __launch_bounds__(256) void vecmat_kernel(
    const float* __restrict__ in, const float* __restrict__ W,
    const float* __restrict__ bias, float* __restrict__ outp) {
  const int b = blockIdx.x >> 5;
  const int n0 = (blockIdx.x & 31) * 32;
  const int lane = threadIdx.x & 63;
  const int w = threadIdx.x >> 6;
  float4 qv[4];
#pragma unroll
  for (int it = 0; it < 4; ++it)
    qv[it] = *(const float4*)&in[(long)b * DM + it * 256 + lane * 4];
#pragma unroll
  for (int j = 0; j < 8; ++j) {
    const int n = n0 + w * 8 + j;
    const float* wrow = W + (long)n * DM;
    float s = 0.f;
#pragma unroll
    for (int it = 0; it < 4; ++it) {
      float4 wv = *(const float4*)&wrow[it * 256 + lane * 4];
      s += qv[it].x * wv.x + qv[it].y * wv.y + qv[it].z * wv.z + qv[it].w * wv.w;
    }
    s += __shfl_xor(s, 1);  s += __shfl_xor(s, 2);  s += __shfl_xor(s, 4);
    s += __shfl_xor(s, 8);  s += __shfl_xor(s, 16); s += __shfl_xor(s, 32);
    if (lane == 0) {
      float v = s + bias[n];
      if (ELU) v = v > 0.f ? v + 1.f : __expf(v);
      outp[(long)b * DM + n] = v;
    }
  }
}

// ---- x = (Q . KV) * Z with KV = sum of 4 partials
__global__ __launch_bounds__(256) void xcomp_kernel(
    const float* __restrict__ Q, const float* __restrict__ KVp,
    const float* __restrict__ Ksum, float* __restrict__ xb) {
  const int b = blockIdx.x;
  const int t = threadIdx.x;
  const int h = t >> 4;
  const int m0 = (t & 15) * 4;
  const float* q = Q + (long)b * DM + h * DKH;
  const float* ks = Ksum + (long)b * DM + h * DKH;
  const long kvoff = ((long)b * NH + h) * DKH * DKH;
  const long spstride = (long)NB_B * NH * DKH * DKH;
  float zden = 0.f;
#pragma unroll
  for (int d = 0; d < DKH; ++d) zden += q[d] * ks[d];
  const float z = 1.f / (zden + 1e-6f);
  float nv[4] = {0.f, 0.f, 0.f, 0.f};
  for (int d = 0; d < DKH; ++d) {
    const float qd = q[d];
#pragma unroll
    for (int j = 0; j < 4; ++j) {
      const long idx = kvoff + d * DKH + m0 + j;
      nv[j] += qd * (KVp[idx] + KVp[idx + spstride] +
                     KVp[idx + 2 * spstride] + KVp[idx + 3 * spstride]);
    }
  }
  float* xo = xb + (long)b * DM + h * DKH + m0;
#pragma unroll
  for (int j = 0; j < 4; ++j) xo[j] = nv[j] * z;
}

extern "C" void kernel_launch(void* const* d_in, const int* in_sizes, int n_in,
                              void* d_out, int out_size, void* d_ws, size_t ws_size,
                              hipStream_t stream) {
  (void)in_sizes; (void)n_in; (void)out_size;
  const float* query = (const float*)d_in[0];
  const float* key   = (const float*)d_in[1];
  const float* value = (const float*)d_in[2];
  const float* Wq = (const float*)d_in[3];
  const float* bq = (const float*)d_in[4];
  const float* Wk = (const float*)d_in[5];
  const float* bk = (const float*)d_in[6];
  const float* Wv = (const float*)d_in[7];
  const float* bv = (const float*)d_in[8];
  const float* Wo = (const float*)d_in[9];
  const float* bo = (const float*)d_in[10];
  float* out = (float*)d_out;

  char* p = (char*)d_ws;
  bf16* WkB = (bf16*)p;  p += (size_t)DM * DM * 2;
  bf16* WvB = (bf16*)p;  p += (size_t)DM * DM * 2;
  float* KVp = (float*)p; p += (size_t)4 * NB_B * NH * DKH * DKH * 4;
  float* Ksum = (float*)p; p += (size_t)NB_B * DM * 4;
  float* Q = (float*)p;  p += (size_t)NB_B * DM * 4;
  float* xb = (float*)p; p += (size_t)NB_B * DM * 4;
  const size_t fixed = (size_t)(p - (char*)d_ws);
  const size_t per_b = (size_t)2 * SEQ * DM * 2;  // kT+vT per batch (bf16)
  if (ws_size < fixed + per_b) return;
  int nbc = (int)((ws_size - fixed) / per_b);
  if (nbc > NB_B) nbc = NB_B;
  bf16* kT = (bf16*)p; p += (size_t)nbc * SEQ * DM * 2;
  bf16* vT = (bf16*)p; p += (size_t)nbc * SEQ * DM * 2;

  hipMemsetAsync(Ksum, 0, (size_t)NB_B * DM * 4, stream);
  conv_kernel<<<512, 256, 0, stream>>>(Wk, WkB, (long)DM * DM / 4);
  conv_kernel<<<512, 256, 0, stream>>>(Wv, WvB, (long)DM * DM / 4);
  vecmat_kernel<1><<<NB_B * 32, 256, 0, stream>>>(query, Wq, bq, Q);

  for (int b0 = 0; b0 < NB_B; b0 += nbc) {
    const int nb = (NB_B - b0 < nbc) ? (NB_B - b0) : nbc;
    const int rows = nb * SEQ;
    const int nwg = (rows / 128) * 8;
    gemm128<1><<<nwg, 256, 0, stream>>>(key + (size_t)b0 * SEQ * DM, WkB, bk, kT, Ksum, rows, b0, nwg / 8);
    gemm128<0><<<nwg, 256, 0, stream>>>(value + (size_t)b0 * SEQ * DM, WvB, bv, vT, (float*)nullptr, rows, b0, nwg / 8);
    kv_kernel<<<nb * NH * 4, 256, 0, stream>>>(kT, vT, KVp, rows, b0);
  }

  xcomp_kernel<<<NB_B, 256, 0, stream>>>(Q, KVp, Ksum, xb);
  vecmat_kernel<0><<<NB_B * 32, 256, 0, stream>>>(xb, Wo, bo, out);
}

// Round 10
// 660.532 us; speedup vs baseline: 1.2769x; 1.2769x over previous
//
#include <hip/hip_runtime.h>
#include <hip/hip_bf16.h>
#include <stdint.h>

// LinearMultiHeadedAttention: B=16, S=4096, D=1024, H=16, DK=64
// R10: m97-exact GEMM regime. 128x128 tile, 4 waves, 32 KB LDS single-buf
//      (-> ~4 blocks/CU; inter-block overlap hides the vmcnt(0) drain, m114),
//      both operands bf16 via global_load_lds w/ pre-swizzled source
//      (R2-proven 0-conflict geometry), XCD-ordered grid, plain syncthreads.
//      key/value pre-converted fp32->bf16 (convs run at BW ceiling).

using bf16 = __hip_bfloat16;
typedef __attribute__((ext_vector_type(8))) short short8;  // bf16x8 MFMA frag
typedef __attribute__((ext_vector_type(4))) float f32x4;

#define NB_B 16
#define SEQ 4096
#define DM 1024
#define NH 16
#define DKH 64

__device__ __forceinline__ void gload_lds16(const void* g, void* l) {
  __builtin_amdgcn_global_load_lds((const __attribute__((address_space(1))) void*)g,
                                   (__attribute__((address_space(3))) void*)l, 16, 0, 0);
}

// ---------------- fp32 -> bf16 conversion ----------------
__global__ __launch_bounds__(256) void conv_kernel(const float* __restrict__ src,
                                                   bf16* __restrict__ dst, long n4) {
  long i = (long)blockIdx.x * blockDim.x + threadIdx.x;
  const long stride = (long)gridDim.x * blockDim.x;
  for (; i < n4; i += stride) {
    float4 v = ((const float4*)src)[i];
    union { ushort4 u; bf16 h[4]; } o;
    o.h[0] = __float2bfloat16(v.x);
    o.h[1] = __float2bfloat16(v.y);
    o.h[2] = __float2bfloat16(v.z);
    o.h[3] = __float2bfloat16(v.w);
    ((ushort4*)dst)[i] = o.u;
  }
}

// ---------------- 128x128 4-wave m97-structure GEMM ----------------
// C[row][col] = sum_c A[row][c] * W[col][c]  (+bias[col]); KPROJ: elu+1, Ksum.
// A: bf16 [rowsTot][DM]. W: bf16 [DM][DM]. Out TRANSPOSED bf16 outT[col][row].
// LDS 32 KiB: As[128][64] + Bs[128][64] bf16, 128B rows, single-buffered.
// Swizzle: linear LDS dest (gload_lds) + pre-swizzled global source slot
// ((l&7)^(l>>3)); reads XOR byte ^ ((lane&7)<<4). Measured 0 conflicts (R2/R4).
template <int KPROJ>
__global__ __launch_bounds__(256) void gemm128(
    const bf16* __restrict__ A, const bf16* __restrict__ W,
    const float* __restrict__ bias, bf16* __restrict__ outT,
    float* __restrict__ Ksum, int rowsTot, int b0, int chunk) {
  __shared__ bf16 As[128 * 64];
  __shared__ bf16 Bs[128 * 64];
  const int tid = threadIdx.x;
  const int lane = tid & 63;
  const int wid = tid >> 6;   // 0..3
  const int wr = wid >> 1;    // 0..1 -> 64-row half
  const int wc = wid & 1;     // 0..1 -> 64-col half
  // T1 XCD swizzle: contiguous row-panel chunk per XCD, col-tile fastest.
  const int wgid = (blockIdx.x & 7) * chunk + (blockIdx.x >> 3);
  const int row0 = (wgid >> 3) * 128;
  const int col0 = (wgid & 7) * 128;

  f32x4 acc[4][4] = {};

  const int lr = lane & 15;
  const int xr = (lane & 7) << 4;   // read-side XOR key
  const int lk = (lane >> 4) * 16;  // k-slot byte offset

  // staging: wave w, instr i covers rows w*32 + i*8 + (l>>3);
  // pre-swizzled source slot (l&7)^(l>>3) (dest slot l&7, row&7 == l>>3).
  const bf16* Ab = A + (long)(row0 + wid * 32 + (lane >> 3)) * DM +
                   ((lane & 7) ^ (lane >> 3)) * 8;
  const bf16* Wb = W + (long)(col0 + wid * 32 + (lane >> 3)) * DM +
                   ((lane & 7) ^ (lane >> 3)) * 8;

  for (int kt = 0; kt < 16; ++kt) {
    const int kb = kt * 64;
#pragma unroll
    for (int i = 0; i < 4; ++i)
      gload_lds16(Ab + kb + (long)i * 8 * DM, &As[(wid * 4 + i) * 512]);
#pragma unroll
    for (int i = 0; i < 4; ++i)
      gload_lds16(Wb + kb + (long)i * 8 * DM, &Bs[(wid * 4 + i) * 512]);
    __syncthreads();
#pragma unroll
    for (int kk = 0; kk < 2; ++kk) {
      short8 af[4], bfv[4];
#pragma unroll
      for (int m = 0; m < 4; ++m)
        af[m] = *(const short8*)((char*)As + (wr * 64 + m * 16 + lr) * 128 +
                                 ((kk * 64 + lk) ^ xr));
#pragma unroll
      for (int n = 0; n < 4; ++n)
        bfv[n] = *(const short8*)((char*)Bs + (wc * 64 + n * 16 + lr) * 128 +
                                  ((kk * 64 + lk) ^ xr));
#pragma unroll
      for (int m = 0; m < 4; ++m)
#pragma unroll
        for (int n = 0; n < 4; ++n)
          acc[m][n] = __builtin_amdgcn_mfma_f32_16x16x32_bf16(af[m], bfv[n], acc[m][n], 0, 0, 0);
    }
    __syncthreads();
  }

  // ---- epilogue: bias (+ elu+1 + Ksum), bf16, transposed store
  const int bglob = b0 + (row0 >> 12);
#pragma unroll
  for (int n = 0; n < 4; ++n) {
    const int colg = col0 + wc * 64 + n * 16 + lr;
    const float bv = bias[colg];
    float csum = 0.f;
#pragma unroll
    for (int m = 0; m < 4; ++m) {
      const int r = row0 + wr * 64 + m * 16 + (lane >> 4) * 4;
      union { ushort4 u; bf16 h[4]; } pk;
#pragma unroll
      for (int i = 0; i < 4; ++i) {
        float v = acc[m][n][i] + bv;
        if (KPROJ) { v = v > 0.f ? v + 1.f : __expf(v); csum += v; }
        pk.h[i] = __float2bfloat16(v);
      }
      *(ushort4*)&outT[(long)colg * rowsTot + r] = pk.u;
    }
    if (KPROJ) {
      csum += __shfl_xor(csum, 16);
      csum += __shfl_xor(csum, 32);
      if (lane < 16) atomicAdd(&Ksum[(long)bglob * DM + colg], csum);
    }
  }
}

// ---------------- KV partials: KVp[sp,b,h] = K^T @ V over s-range ----------
__global__ __launch_bounds__(256) void kv_kernel(
    const bf16* __restrict__ KT, const bf16* __restrict__ VT,
    float* __restrict__ KVp, int rowsTot, int b0) {
  const int sp = blockIdx.x & 3;
  const int h = (blockIdx.x >> 2) & 15;
  const int b_loc = blockIdx.x >> 6;
  const int lane = threadIdx.x & 63;
  const int w = threadIdx.x >> 6;
  const long srow = (long)b_loc * SEQ + sp * (SEQ / 4) + ((lane >> 4) * 8);
  const bf16* Ab = KT + (long)(h * DKH + w * 16 + (lane & 15)) * rowsTot + srow;
  const bf16* Bb = VT + (long)(h * DKH + (lane & 15)) * rowsTot + srow;
  f32x4 acc[4] = {};
#pragma unroll 4
  for (int s = 0; s < SEQ / 4; s += 32) {
    short8 a = *(const short8*)(Ab + s);
#pragma unroll
    for (int n = 0; n < 4; ++n) {
      short8 bv = *(const short8*)(Bb + (long)n * 16 * rowsTot + s);
      acc[n] = __builtin_amdgcn_mfma_f32_16x16x32_bf16(a, bv, acc[n], 0, 0, 0);
    }
  }
  float* o = KVp + (((long)sp * NB_B + (b0 + b_loc)) * NH + h) * DKH * DKH;
#pragma unroll
  for (int n = 0; n < 4; ++n)
#pragma unroll
    for (int i = 0; i < 4; ++i)
      o[(w * 16 + (lane >> 4) * 4 + i) * DKH + n * 16 + (lane & 15)] = acc[n][i];
}

// ---------------- small fp32 vec-mat ----------------
template <int ELU>
__global__ __launch_bounds__(256) void vecmat_kernel(
    const float* __restrict__ in, const float* __restrict__ W,
    const float* __restrict__ bias, float* __restrict__ outp) {
  const int b = blockIdx.x >> 5;
  const int n0 = (blockIdx.x & 31) * 32;
  const int lane = threadIdx.x & 63;
  const int w = threadIdx.x >> 6;
  float4 qv[4];
#pragma unroll
  for (int it = 0; it < 4; ++it)
    qv[it] = *(const float4*)&in[(long)b * DM + it * 256 + lane * 4];
#pragma unroll
  for (int j = 0; j < 8; ++j) {
    const int n = n0 + w * 8 + j;
    const float* wrow = W + (long)n * DM;
    float s = 0.f;
#pragma unroll
    for (int it = 0; it < 4; ++it) {
      float4 wv = *(const float4*)&wrow[it * 256 + lane * 4];
      s += qv[it].x * wv.x + qv[it].y * wv.y + qv[it].z * wv.z + qv[it].w * wv.w;
    }
    s += __shfl_xor(s, 1);  s += __shfl_xor(s, 2);  s += __shfl_xor(s, 4);
    s += __shfl_xor(s, 8);  s += __shfl_xor(s, 16); s += __shfl_xor(s, 32);
    if (lane == 0) {
      float v = s + bias[n];
      if (ELU) v = v > 0.f ? v + 1.f : __expf(v);
      outp[(long)b * DM + n] = v;
    }
  }
}

// ---- x = (Q . KV) * Z with KV = sum of 4 partials
__global__ __launch_bounds__(256) void xcomp_kernel(
    const float* __restrict__ Q, const float* __restrict__ KVp,
    const float* __restrict__ Ksum, float* __restrict__ xb) {
  const int b = blockIdx.x;
  const int t = threadIdx.x;
  const int h = t >> 4;
  const int m0 = (t & 15) * 4;
  const float* q = Q + (long)b * DM + h * DKH;
  const float* ks = Ksum + (long)b * DM + h * DKH;
  const long kvoff = ((long)b * NH + h) * DKH * DKH;
  const long spstride = (long)NB_B * NH * DKH * DKH;
  float zden = 0.f;
#pragma unroll
  for (int d = 0; d < DKH; ++d) zden += q[d] * ks[d];
  const float z = 1.f / (zden + 1e-6f);
  float nv[4] = {0.f, 0.f, 0.f, 0.f};
  for (int d = 0; d < DKH; ++d) {
    const float qd = q[d];
#pragma unroll
    for (int j = 0; j < 4; ++j) {
      const long idx = kvoff + d * DKH + m0 + j;
      nv[j] += qd * (KVp[idx] + KVp[idx + spstride] +
                     KVp[idx + 2 * spstride] + KVp[idx + 3 * spstride]);
    }
  }
  float* xo = xb + (long)b * DM + h * DKH + m0;
#pragma unroll
  for (int j = 0; j < 4; ++j) xo[j] = nv[j] * z;
}

extern "C" void kernel_launch(void* const* d_in, const int* in_sizes, int n_in,
                              void* d_out, int out_size, void* d_ws, size_t ws_size,
                              hipStream_t stream) {
  (void)in_sizes; (void)n_in; (void)out_size;
  const float* query = (const float*)d_in[0];
  const float* key   = (const float*)d_in[1];
  const float* value = (const float*)d_in[2];
  const float* Wq = (const float*)d_in[3];
  const float* bq = (const float*)d_in[4];
  const float* Wk = (const float*)d_in[5];
  const float* bk = (const float*)d_in[6];
  const float* Wv = (const float*)d_in[7];
  const float* bv = (const float*)d_in[8];
  const float* Wo = (const float*)d_in[9];
  const float* bo = (const float*)d_in[10];
  float* out = (float*)d_out;

  char* p = (char*)d_ws;
  bf16* WkB = (bf16*)p;  p += (size_t)DM * DM * 2;
  bf16* WvB = (bf16*)p;  p += (size_t)DM * DM * 2;
  float* KVp = (float*)p; p += (size_t)4 * NB_B * NH * DKH * DKH * 4;
  float* Ksum = (float*)p; p += (size_t)NB_B * DM * 4;
  float* Q = (float*)p;  p += (size_t)NB_B * DM * 4;
  float* xb = (float*)p; p += (size_t)NB_B * DM * 4;
  const size_t fixed = (size_t)(p - (char*)d_ws);
  const size_t per_b = (size_t)4 * SEQ * DM * 2;  // keyB+valB+kT+vT per batch
  if (ws_size < fixed + per_b) return;
  int nbc = (int)((ws_size - fixed) / per_b);
  if (nbc > NB_B) nbc = NB_B;
  bf16* keyB = (bf16*)p; p += (size_t)nbc * SEQ * DM * 2;
  bf16* valB = (bf16*)p; p += (size_t)nbc * SEQ * DM * 2;
  bf16* kT   = (bf16*)p; p += (size_t)nbc * SEQ * DM * 2;
  bf16* vT   = (bf16*)p; p += (size_t)nbc * SEQ * DM * 2;

  hipMemsetAsync(Ksum, 0, (size_t)NB_B * DM * 4, stream);
  conv_kernel<<<512, 256, 0, stream>>>(Wk, WkB, (long)DM * DM / 4);
  conv_kernel<<<512, 256, 0, stream>>>(Wv, WvB, (long)DM * DM / 4);
  vecmat_kernel<1><<<NB_B * 32, 256, 0, stream>>>(query, Wq, bq, Q);

  for (int b0 = 0; b0 < NB_B; b0 += nbc) {
    const int nb = (NB_B - b0 < nbc) ? (NB_B - b0) : nbc;
    const int rows = nb * SEQ;
    const long n4 = (long)rows * DM / 4;
    conv_kernel<<<2048, 256, 0, stream>>>(key + (size_t)b0 * SEQ * DM, keyB, n4);
    conv_kernel<<<2048, 256, 0, stream>>>(value + (size_t)b0 * SEQ * DM, valB, n4);
    const int nwg = (rows / 128) * 8;
    gemm128<1><<<nwg, 256, 0, stream>>>(keyB, WkB, bk, kT, Ksum, rows, b0, nwg / 8);
    gemm128<0><<<nwg, 256, 0, stream>>>(valB, WvB, bv, vT, (float*)nullptr, rows, b0, nwg / 8);
    kv_kernel<<<nb * NH * 4, 256, 0, stream>>>(kT, vT, KVp, rows, b0);
  }

  xcomp_kernel<<<NB_B, 256, 0, stream>>>(Q, KVp, Ksum, xb);
  vecmat_kernel<0><<<NB_B * 32, 256, 0, stream>>>(xb, Wo, bo, out);
}